// Round 2
// baseline (913.154 us; speedup 1.0000x reference)
//
#include <hip/hip_runtime.h>

// Problem constants
#define T_STEPS 256
#define B_SZ    4096
#define I_SZ    144
#define H_SZ    32
#define W_LD    176   // H + I
#define VPAD    192   // padded v length: 8 segments x 24 floats

// photonic sigmoid constants
#define PS_A1   0.06f
#define PS_A2   1.005f
#define PS_X0   0.145f
#define PS_D    0.033f
#define PS_CUT  2.0f

typedef const __attribute__((address_space(1))) float* gas_fp;
typedef __attribute__((address_space(3))) float* las_fp;

__device__ __forceinline__ void dma16(const float* g, float* l) {
    // 16B per active lane, LDS dest = wave-uniform base + lane*16
    __builtin_amdgcn_global_load_lds((gas_fp)g, (las_fp)l, 16, 0, 0);
}

// packed 2xfp32 FMA (dual-rate on CDNA): d = a*b + c elementwise
__device__ __forceinline__ float2 pkfma(float2 a, float2 b, float2 c) {
    float2 d;
    asm("v_pk_fma_f32 %0, %1, %2, %3" : "=v"(d) : "v"(a), "v"(b), "v"(c));
    return d;
}

__device__ __forceinline__ float psig(float z) {
    const float expC = (float)(1.0 / (0.033 * 0.6931471805599453)); // 1/(D*ln2)
    float zz = fminf(z - PS_X0, PS_CUT);
    float e  = exp2f(zz * expC);
#if __has_builtin(__builtin_amdgcn_rcpf)
    float r = __builtin_amdgcn_rcpf(1.0f + e);
#else
    float r = 1.0f / (1.0f + e);
#endif
    return fmaf(PS_A1 - PS_A2, r, PS_A2);
}

// -----------------------------------------------------------------------------
// Fused kernel: 1 wave = 1 batch chain, all 256 steps.
// lane = (s, j): s = tid>>3 in [0,8) = 24-wide k-segment of padded v[192],
// j = tid&7. Lane computes partials for 4 outputs {j, j+8, j+16, j+24} over
// its segment: 96 FMAs as 48 v_pk_fma_f32, fed by 6 ds_read_b128 (2-way bank
// alias = free). Reduction over 8 segments = reduce-scatter: xor8 (2 shfl,
// values 4->2), xor16 (1 shfl, 2->1), xor32 (1 shfl) -> each lane owns ONE
// complete output row; one psig; lanes 0..31 publish h via conflict-free
// 32-bank ds_write. x_t DMA'd 2 steps ahead via global_load_lds, counted
// vmcnt(2) keeps 2 loads in flight across iterations.
// -----------------------------------------------------------------------------
__global__ __launch_bounds__(64, 3) void fused_rnn(
    const float* __restrict__ x,     // [256][4096][144]
    const float* __restrict__ W,     // [32][176]  (Wh = cols 0..31, Wx = 32..175)
    const float* __restrict__ bias,  // [32]
    float* __restrict__ out)         // [4096][32]
{
    const int tid = threadIdx.x;
    const int j   = tid & 7;
    const int s   = tid >> 3;
    const int b   = blockIdx.x;

    __shared__ float vbuf[4][VPAD];  // [ring][ h(32) | x(144) | zero-pad(16) ]

    // ---- one-time: weight slices -> registers (t-invariant) ----
    // rows {j, j+8, j+16, j+24}, cols [24s, 24s+24), zero-padded past 176.
    float2 wp[4][12];
#pragma unroll
    for (int r = 0; r < 4; ++r) {
        const float* wr = W + (j + 8 * r) * W_LD;
#pragma unroll
        for (int i = 0; i < 6; ++i) {
            int col = 24 * s + 4 * i;
            float4 wv = (col < W_LD) ? *(const float4*)(wr + col)
                                     : make_float4(0.f, 0.f, 0.f, 0.f);
            wp[r][2*i]   = make_float2(wv.x, wv.y);
            wp[r][2*i+1] = make_float2(wv.z, wv.w);
        }
    }

    // after reduce-scatter this lane owns output row:
    const int bit3 = s & 1;
    const int bit4 = (s >> 1) & 1;
    const int outrow = j + 8 * (2 * bit3 + bit4);
    const float bsr = bias[outrow];

    // drain one-time loads so loop vmcnt counts only DMAs
    asm volatile("s_waitcnt vmcnt(0)" ::: "memory");

    // init: h0 = 0 in ring slot 0; zero-pad v[176..191] of all 4 slots
    if (tid < 32) vbuf[0][tid] = 0.0f;
    vbuf[tid >> 4][176 + (tid & 15)] = 0.0f;

    const size_t tstride = (size_t)B_SZ * I_SZ;          // floats per t-slab
    const float* xrow = x + (size_t)b * I_SZ + tid * 4;  // lane's 16B slot
    const bool ld = (tid < 36);                          // 36*16B = 576B row

    if (ld) {
        dma16(xrow,           &vbuf[0][H_SZ]);           // x[0]
        dma16(xrow + tstride, &vbuf[1][H_SZ]);           // x[1]
    }
    const float* xsrc = xrow + 2 * tstride;              // next DMA src: x[t+2]

    float h = 0.0f;

    for (int t = 0; t < T_STEPS; ++t) {
        // issue prefetch for t+2 (clamped dups at the tail keep counts uniform)
        if (ld) dma16(xsrc, &vbuf[(t + 2) & 3][H_SZ]);
        if (t < T_STEPS - 3) xsrc += tstride;

        // wait for x[t] only; keep 2 DMAs in flight across the iteration
        asm volatile("s_waitcnt vmcnt(2)" ::: "memory");
        __builtin_amdgcn_sched_barrier(0);

        const float* vb = &vbuf[t & 3][24 * s];
        float2 a0 = make_float2(0.f, 0.f), a1 = a0, a2 = a0, a3 = a0;
#pragma unroll
        for (int i = 0; i < 6; ++i) {
            float4 v = *(const float4*)(vb + 4 * i);     // broadcast ds_read_b128
            float2 vlo = make_float2(v.x, v.y);
            float2 vhi = make_float2(v.z, v.w);
            a0 = pkfma(wp[0][2*i], vlo, a0); a0 = pkfma(wp[0][2*i+1], vhi, a0);
            a1 = pkfma(wp[1][2*i], vlo, a1); a1 = pkfma(wp[1][2*i+1], vhi, a1);
            a2 = pkfma(wp[2][2*i], vlo, a2); a2 = pkfma(wp[2][2*i+1], vhi, a2);
            a3 = pkfma(wp[3][2*i], vlo, a3); a3 = pkfma(wp[3][2*i+1], vhi, a3);
        }
        float p0 = a0.x + a0.y, p1 = a1.x + a1.y;
        float p2 = a2.x + a2.y, p3 = a3.x + a3.y;

        // ---- reduce-scatter over the 8 segments ----
        // stage A (xor 8): 4 values -> 2; lane keeps rows {j,j+8} (bit3=0)
        // or {j+16,j+24} (bit3=1)
        float ua = bit3 ? p0 : p2;
        float ub = bit3 ? p1 : p3;
        float uas = __shfl_xor(ua, 8, 64);
        float ubs = __shfl_xor(ub, 8, 64);
        float q0 = (bit3 ? p2 : p0) + uas;
        float q1 = (bit3 ? p3 : p1) + ubs;

        // stage B (xor 16): 2 -> 1; lane owns row `outrow`
        float w0 = bit4 ? q0 : q1;
        float wsv = __shfl_xor(w0, 16, 64);
        float z   = (bit4 ? q1 : q0) + wsv;

        // stage C (xor 32): combine segment quads -> complete sum
        z += __shfl_xor(z, 32, 64);

        h = psig(z + bsr);

        // publish h for step t+1: lanes 0..31 cover all 32 rows, 32 banks
        if (s < 4) vbuf[(t + 1) & 3][outrow] = h;
    }

    if (s < 4) out[(size_t)b * H_SZ + outrow] = h;
}

// -----------------------------------------------------------------------------
extern "C" void kernel_launch(void* const* d_in, const int* in_sizes, int n_in,
                              void* d_out, int out_size, void* d_ws, size_t ws_size,
                              hipStream_t stream)
{
    const float* x    = (const float*)d_in[0];  // [256][4096][144]
    const float* W    = (const float*)d_in[1];  // [32][176]
    const float* bias = (const float*)d_in[2];  // [32]
    float* out = (float*)d_out;                 // [4096][32]
    (void)d_ws; (void)ws_size; (void)in_sizes; (void)n_in; (void)out_size;

    fused_rnn<<<B_SZ, 64, 0, stream>>>(x, W, bias, out);
}